// Round 18
// baseline (271.545 us; speedup 1.0000x reference)
//
#include <hip/hip_runtime.h>

typedef __bf16 bf16;
typedef __bf16 bf16x4 __attribute__((ext_vector_type(4)));
typedef __bf16 bf16x8 __attribute__((ext_vector_type(8)));
typedef float  f32x4  __attribute__((ext_vector_type(4)));

#define MFMA16(a, b, c) __builtin_amdgcn_mfma_f32_16x16x32_bf16((a), (b), (c), 0, 0, 0)

// async global->LDS, 16B per lane; LDS dest = wave-uniform base + lane*16
__device__ __forceinline__ void async_copy16(const void* g, void* l) {
  __builtin_amdgcn_global_load_lds(
      (const __attribute__((address_space(1))) unsigned int*)g,
      (__attribute__((address_space(3))) unsigned int*)l, 16, 0, 0);
}

// ------------------------------------------------- fused f32->bf16 (5 segments)
// R27: seg 1 (Wq) is pre-scaled by 0.125*log2(e) in f32 (exact until the one
// bf16 rounding), so Q emerges from the QK GEMM already in the log2 domain
// and k_attn's softmax needs NO per-element multiply (exp2f direct).
struct CvtArgs {
  const float* src[5];
  bf16* dst[5];
  int blk_start[6];
};
__global__ void k_cvt_all(CvtArgs a) {
  int b = blockIdx.x;
  int seg = 0;
#pragma unroll
  for (int s = 1; s < 5; ++s) seg += (b >= a.blk_start[s]);
  int i = (b - a.blk_start[seg]) * 2048 + threadIdx.x * 8;
  float4 v0 = *(const float4*)(a.src[seg] + i);
  float4 v1 = *(const float4*)(a.src[seg] + i + 4);
  float sc = (seg == 1) ? 0.18033688f : 1.0f;  // 0.125*log2(e) for Wq
  bf16x8 o = { (bf16)(v0.x * sc), (bf16)(v0.y * sc), (bf16)(v0.z * sc), (bf16)(v0.w * sc),
               (bf16)(v1.x * sc), (bf16)(v1.y * sc), (bf16)(v1.z * sc), (bf16)(v1.w * sc) };
  *(bf16x8*)(a.dst[seg] + i) = o;
}

// ------------------------------------------- 128x128-tile GEMM body, BK=64
// C[m][n] = sum_k A[m][k]*B[n][k] (A MxK, B NxK row-major bf16 => A@B^T).
// R25: PERMB variant permutes B-operand SOURCE rows within each 64-row
// window (klog->kv: s -> (s&0x23)|((s&0x04)<<2)|((s&0x18)>>1)) so the V^T
// output lands with pre-permuted columns. Consumed only by k_attn, whose PV
// B-frag is then a single contiguous b128 (ak-style). Verified R25: attn
// conflicts 4.2M -> 0, 87.0 -> 81.0 us.
template <int OUTF32, int PERMB = 0>
__device__ __forceinline__ void gemm128_body(
    const bf16* __restrict__ A, const bf16* __restrict__ B, void* __restrict__ Cp,
    const float* __restrict__ bias, int m0, int n0, int N, int K) {
  __shared__ alignas(16) bf16 As[2][128 * 32];
  __shared__ alignas(16) bf16 Bs[2][128 * 32];
  const int tid = threadIdx.x;
  const int lane = tid & 63;
  const int w = tid >> 6;
  const int quad = lane >> 4;
  const int l16 = lane & 15;
  const int wr = (w >> 1) * 64;
  const int wc = (w & 1) * 64;

  const int srow = tid >> 2;
  const int skk = (tid & 3) * 8;
  const int srowB =
      PERMB ? ((srow & 0x23) | ((srow & 0x04) << 2) | ((srow & 0x18) >> 1)) : srow;
  const bf16* Ag = A + (long)(m0 + srow) * K + skk;
  const bf16* Bg = B + (long)(n0 + srowB) * K + skk;
  const long half = 64L * K;
  bf16* AsW0 = As[0] + w * 512;
  bf16* BsW0 = Bs[0] + w * 512;
  bf16* AsW1 = As[1] + w * 512;
  bf16* BsW1 = Bs[1] + w * 512;

  f32x4 acc[4][4];
#pragma unroll
  for (int i = 0; i < 4; ++i)
#pragma unroll
    for (int j = 0; j < 4; ++j) acc[i][j] = (f32x4){0.f, 0.f, 0.f, 0.f};

  for (int k0 = 0; k0 < K; k0 += 64) {
    async_copy16(Ag + k0, AsW0);
    async_copy16(Ag + half + k0, AsW0 + 2048);
    async_copy16(Bg + k0, BsW0);
    async_copy16(Bg + half + k0, BsW0 + 2048);
    async_copy16(Ag + k0 + 32, AsW1);
    async_copy16(Ag + half + k0 + 32, AsW1 + 2048);
    async_copy16(Bg + k0 + 32, BsW1);
    async_copy16(Bg + half + k0 + 32, BsW1 + 2048);
    __syncthreads();
#pragma unroll
    for (int p = 0; p < 2; ++p) {
      const bf16* AsP = As[p];
      const bf16* BsP = Bs[p];
      bf16x8 af[4], bfr[4];
#pragma unroll
      for (int i = 0; i < 4; ++i)
        af[i] = *(const bf16x8*)&AsP[(wr + i * 16 + l16) * 32 + quad * 8];
#pragma unroll
      for (int j = 0; j < 4; ++j)
        bfr[j] = *(const bf16x8*)&BsP[(wc + j * 16 + l16) * 32 + quad * 8];
#pragma unroll
      for (int i = 0; i < 4; ++i)
#pragma unroll
        for (int j = 0; j < 4; ++j) acc[i][j] = MFMA16(af[i], bfr[j], acc[i][j]);
    }
    __syncthreads();
  }

#pragma unroll
  for (int i = 0; i < 4; ++i)
#pragma unroll
    for (int j = 0; j < 4; ++j)
#pragma unroll
      for (int r = 0; r < 4; ++r) {
        long row = m0 + wr + i * 16 + quad * 4 + r;
        int col = n0 + wc + j * 16 + l16;
        if (OUTF32)
          ((float*)Cp)[row * N + col] = acc[i][j][r] + bias[col];
        else
          ((bf16*)Cp)[row * N + col] = (bf16)acc[i][j][r];
      }
}

// Combined QK-projection (bid<1024) + V^T (bid>=1024), SINGLE body call.
// launch_bounds(256,4): best measured. Index maps keep the LARGE operand (xb)
// XCD-local: same-tile readers 64 block-ids apart (64 % 8 == 0).
__global__ __launch_bounds__(256, 4) void k_gemm_qkv(
    const bf16* __restrict__ xb, const bf16* __restrict__ Wqk, bf16* __restrict__ QKb,
    const bf16* __restrict__ Wvb, bf16* __restrict__ VtG) {
  int bid = blockIdx.x;
  if (bid < 1024) {
    gemm128_body<0, 0>(xb, Wqk, QKb, nullptr,
                       (bid & 63) * 128, (bid >> 6) * 128, 2048, 1024);
  } else {
    int id = bid - 1024;
    // V^T with kv-permuted columns (PERMB=1) — consumed only by k_attn.
    gemm128_body<0, 1>(Wvb, xb, VtG, nullptr,
                       (id >> 6) * 128, (id & 63) * 128, 8192, 1024);
  }
}

__global__ __launch_bounds__(256, 4) void k_gemm_out(
    const bf16* __restrict__ Ab, const bf16* __restrict__ Wub, float* __restrict__ out,
    const float* __restrict__ bu) {
  gemm128_body<1, 0>(Ab, Wub, out, bu, blockIdx.x * 128, blockIdx.y * 128, 1024, 1024);
}

// --------------------------------------------------------- flash attention
// R27 = verified R25 body (81.0 us, conflicts 0, 87% combined pipe issue;
// VALU-issue-bound) minus per-iter VALU:
//  - Wq pre-scaled by 0.125*log2e at cvt (f32-exact path) -> st arrives in
//    the log2 domain; exp = exp2f (bare v_exp_f32, compiler-generated with
//    proper trans hazards — NOT R5's raw inline asm). Kills 64 v_mul/wave-
//    iter; bq becomes raw bf16 loads (no conversion).
//  - T5 setprio(1) around the QK^T and PV MFMA clusters (m191: +4-7% attn
//    with phase-diverse waves; our CU hosts 2 independent blocks).
__global__ __launch_bounds__(256, 2) void k_attn(
    const bf16* __restrict__ Q, const bf16* __restrict__ Kb,
    const bf16* __restrict__ Vt, bf16* __restrict__ O) {
  __shared__ alignas(16) bf16 Ks[2][64 * 64];  // [buf][kv][d]   (swizzled 16B chunks)
  __shared__ alignas(16) bf16 Vs[2][64 * 64];  // [buf][d][klog] (swizzled 16B chunks)

  const int tid = threadIdx.x;
  const int lane = tid & 63;
  const int w = tid >> 6;
  const int quad = lane >> 4;
  const int l16 = lane & 15;
  const int hsw = l16 & 7;        // read-side swizzle key (row&7)
  const int bh = blockIdx.x;      // 0..63 (fast dim -> XCD = bh & 7)
  const int qt = blockIdx.y;      // 0..7 (256-row q tiles)
  const int bb = bh >> 4;
  const int h = bh & 15;
  const int hoff = h * 64;
  const long rowQ0 = (long)bb * 2048 + qt * 256;
  const long kv0 = (long)bb * 2048;

  // ---- Q B-frags direct from global (already scaled at cvt; raw loads)
  bf16x8 bq[4][2];
#pragma unroll
  for (int g = 0; g < 4; ++g)
#pragma unroll
    for (int ss = 0; ss < 2; ++ss)
      bq[g][ss] = *(const bf16x8*)(Q + (rowQ0 + w * 64 + g * 16 + l16) * 2048 +
                                   hoff + ss * 32 + quad * 8);

  f32x4 accO[4][4];
  f32x4 accS[4];
#pragma unroll
  for (int g = 0; g < 4; ++g) {
    accS[g] = (f32x4){0.f, 0.f, 0.f, 0.f};
#pragma unroll
    for (int t = 0; t < 4; ++t) accO[g][t] = (f32x4){0.f, 0.f, 0.f, 0.f};
  }

  // ---- staging addressing: thread L covers rows (L>>3) and (L>>3)+32 of the
  // 64-row tile; source col pre-swizzled so phys chunk p holds logical chunk
  // p^(row&7)  (same key as the reads). V columns are ALREADY kv-permuted in
  // VtG (GEMM-side), so V staging is identical in form to K staging.
  const int rr = tid >> 3;                       // 0..31
  const int cc8 = ((tid & 7) ^ (rr & 7)) * 8;    // source col (elems)
  const bf16* ksrc = Kb + (kv0 + rr) * 2048 + hoff + cc8;
  const bf16* vsrc = Vt + (long)(hoff + rr) * 8192 + kv0 + cc8;
  const int dstOff = w * 512;                    // wave-uniform LDS base (elems)

  // prologue: stage tile 0 into buf0
  async_copy16(ksrc, Ks[0] + dstOff);
  async_copy16(ksrc + 32 * 2048, Ks[0] + 2048 + dstOff);
  async_copy16(vsrc, Vs[0] + dstOff);
  async_copy16(vsrc + 32 * 8192, Vs[0] + 2048 + dstOff);
  ksrc += 64 * 2048;
  vsrc += 64;

  const bf16 onev = (bf16)1.0f;
  const bf16x8 ones8 = {onev, onev, onev, onev, onev, onev, onev, onev};

  for (int kt = 0; kt < 32; ++kt) {
    __syncthreads();  // drains this wave's stage(kt) (vmcnt 0) + syncs block
    if (kt < 31) {    // async prefetch of tile kt+1 into the other buffer
      bf16* kb = Ks[(kt + 1) & 1];
      bf16* vb = Vs[(kt + 1) & 1];
      async_copy16(ksrc, kb + dstOff);
      async_copy16(ksrc + 32 * 2048, kb + 2048 + dstOff);
      async_copy16(vsrc, vb + dstOff);
      async_copy16(vsrc + 32 * 8192, vb + 2048 + dstOff);
      ksrc += 64 * 2048;
      vsrc += 64;
    }
    const bf16* kbuf = Ks[kt & 1];
    const bf16* vbuf = Vs[kt & 1];

    // K A-frags: logical 16B chunk c = s*4+quad at row mt*16+l16, phys = c^hsw
    bf16x8 ak[4][2];
#pragma unroll
    for (int mt = 0; mt < 4; ++mt) {
      const int rb = (mt * 16 + l16) * 64;
      ak[mt][0] = *(const bf16x8*)&kbuf[rb + ((quad ^ hsw) * 8)];
      ak[mt][1] = *(const bf16x8*)&kbuf[rb + (((4 + quad) ^ hsw) * 8)];
    }
    // V B-frags: storage col pre-permuted, so logical chunk c = ss*4+quad at
    // row t*16+l16, phys = c^hsw — single b128, identical pattern to ak.
    bf16x8 bv[2][4];
#pragma unroll
    for (int ss = 0; ss < 2; ++ss)
#pragma unroll
      for (int t = 0; t < 4; ++t) {
        const int rb = (t * 16 + l16) * 64;
        bv[ss][t] = *(const bf16x8*)&vbuf[rb + (((ss * 4 + quad) ^ hsw) * 8)];
      }

#pragma unroll
    for (int g = 0; g < 4; ++g) {
      // S^T[kv][qrow] = K Q^T for this q-group (log2-domain: Wq pre-scaled)
      f32x4 st[4];
      __builtin_amdgcn_s_setprio(1);
#pragma unroll
      for (int mt = 0; mt < 4; ++mt) {
        st[mt] = (f32x4){0.f, 0.f, 0.f, 0.f};
        st[mt] = MFMA16(ak[mt][0], bq[g][0], st[mt]);
        st[mt] = MFMA16(ak[mt][1], bq[g][1], st[mt]);
      }
      __builtin_amdgcn_s_setprio(0);
      // max-free softmax in registers (permuted contraction axis):
      // apf[ss][4b+r] = exp2(st[2ss+b][r])  <->  kv = 32ss+16b+4quad+r
      bf16x8 apf[2];
#pragma unroll
      for (int mt = 0; mt < 4; ++mt) {
#pragma unroll
        for (int r = 0; r < 4; ++r) {
          float pv = exp2f(st[mt][r]);
          apf[mt >> 1][(mt & 1) * 4 + r] = (bf16)pv;
        }
      }
      // O += P V ; row sums via ones-column MFMA (no VALU adds, no shuffles)
      __builtin_amdgcn_s_setprio(1);
#pragma unroll
      for (int ss = 0; ss < 2; ++ss) {
#pragma unroll
        for (int t = 0; t < 4; ++t)
          accO[g][t] = MFMA16(apf[ss], bv[ss][t], accO[g][t]);
        accS[g] = MFMA16(apf[ss], ones8, accS[g]);
      }
      __builtin_amdgcn_s_setprio(0);
    }
  }

  // epilogue: accS[g][r] holds rowsum(qrow=quad*4+r) in every lane
#pragma unroll
  for (int g = 0; g < 4; ++g)
#pragma unroll
    for (int r = 0; r < 4; ++r) {
      float inv = 1.f / accS[g][r];
      long row = rowQ0 + w * 64 + g * 16 + quad * 4 + r;
#pragma unroll
      for (int t = 0; t < 4; ++t)
        O[row * 1024 + hoff + t * 16 + l16] = (bf16)(accO[g][t][r] * inv);
    }
}

// ----------------------------------------------------------------- launch
extern "C" void kernel_launch(void* const* d_in, const int* in_sizes, int n_in,
                              void* d_out, int out_size, void* d_ws, size_t ws_size,
                              hipStream_t stream) {
  const float* x  = (const float*)d_in[0];
  const float* Wk = (const float*)d_in[1];
  const float* Wq = (const float*)d_in[2];
  const float* Wv = (const float*)d_in[3];
  const float* Wu = (const float*)d_in[4];
  const float* bu = (const float*)d_in[5];
  float* out = (float*)d_out;

  const int XE = 4 * 2048 * 1024;  // 8388608
  const int WE = 1024 * 1024;      // 1048576

  bf16* p = (bf16*)d_ws;
  bf16* xb   = p; p += XE;
  bf16* Wqkb = p; p += 2 * WE;  // Wq rows (pre-scaled) | Wk rows
  bf16* Wvb  = p; p += WE;
  bf16* Wub  = p; p += WE;
  bf16* QKb  = p; p += 2 * XE;  // [8192][2048]: Q (log2-domain) | K
  bf16* VtG  = p; p += XE;      // V^T [1024][8192] (kv-permuted cols)
  bf16* Ab   = p; p += XE;      // attention output [8192][1024]

  CvtArgs ca;
  ca.src[0] = x;  ca.dst[0] = xb;
  ca.src[1] = Wq; ca.dst[1] = Wqkb;
  ca.src[2] = Wk; ca.dst[2] = Wqkb + WE;
  ca.src[3] = Wv; ca.dst[3] = Wvb;
  ca.src[4] = Wu; ca.dst[4] = Wub;
  ca.blk_start[0] = 0;
  ca.blk_start[1] = XE / 2048;                 // 4096
  ca.blk_start[2] = ca.blk_start[1] + WE / 2048;
  ca.blk_start[3] = ca.blk_start[2] + WE / 2048;
  ca.blk_start[4] = ca.blk_start[3] + WE / 2048;
  ca.blk_start[5] = ca.blk_start[4] + WE / 2048;  // 6144 total
  k_cvt_all<<<ca.blk_start[5], 256, 0, stream>>>(ca);

  k_gemm_qkv<<<1536, 256, 0, stream>>>(xb, Wqkb, QKb, Wvb, VtG);

  // grid: bh fast (XCD-aligned K/V reuse), qt slow
  k_attn<<<dim3(64, 8), 256, 0, stream>>>(QKb, QKb + 1024, VtG, Ab);

  k_gemm_out<<<dim3(64, 8), 256, 0, stream>>>(Ab, Wub, out, bu);
}

// Round 20
// 243.718 us; speedup vs baseline: 1.1142x; 1.1142x over previous
//
#include <hip/hip_runtime.h>

typedef __bf16 bf16;
typedef __bf16 bf16x4 __attribute__((ext_vector_type(4)));
typedef __bf16 bf16x8 __attribute__((ext_vector_type(8)));
typedef float  f32x4  __attribute__((ext_vector_type(4)));

#define MFMA16(a, b, c) __builtin_amdgcn_mfma_f32_16x16x32_bf16((a), (b), (c), 0, 0, 0)

// async global->LDS, 16B per lane; LDS dest = wave-uniform base + lane*16
__device__ __forceinline__ void async_copy16(const void* g, void* l) {
  __builtin_amdgcn_global_load_lds(
      (const __attribute__((address_space(1))) unsigned int*)g,
      (__attribute__((address_space(3))) unsigned int*)l, 16, 0, 0);
}

// ------------------------------------------------- fused f32->bf16 (5 segments)
// R27: seg 1 (Wq) is pre-scaled by 0.125*log2(e) in f32 (exact until the one
// bf16 rounding), so Q emerges from the QK GEMM already in the log2 domain.
// Verified numerically OK in R27 (absmax 1.95e-3, passed).
struct CvtArgs {
  const float* src[5];
  bf16* dst[5];
  int blk_start[6];
};
__global__ void k_cvt_all(CvtArgs a) {
  int b = blockIdx.x;
  int seg = 0;
#pragma unroll
  for (int s = 1; s < 5; ++s) seg += (b >= a.blk_start[s]);
  int i = (b - a.blk_start[seg]) * 2048 + threadIdx.x * 8;
  float4 v0 = *(const float4*)(a.src[seg] + i);
  float4 v1 = *(const float4*)(a.src[seg] + i + 4);
  float sc = (seg == 1) ? 0.18033688f : 1.0f;  // 0.125*log2(e) for Wq
  bf16x8 o = { (bf16)(v0.x * sc), (bf16)(v0.y * sc), (bf16)(v0.z * sc), (bf16)(v0.w * sc),
               (bf16)(v1.x * sc), (bf16)(v1.y * sc), (bf16)(v1.z * sc), (bf16)(v1.w * sc) };
  *(bf16x8*)(a.dst[seg] + i) = o;
}

// ------------------------------------------- 128x128-tile GEMM body, BK=64
// C[m][n] = sum_k A[m][k]*B[n][k] (A MxK, B NxK row-major bf16 => A@B^T).
// R25: PERMB variant permutes B-operand SOURCE rows within each 64-row
// window (klog->kv: s -> (s&0x23)|((s&0x04)<<2)|((s&0x18)>>1)) so the V^T
// output lands with pre-permuted columns. Consumed only by k_attn, whose PV
// B-frag is then a single contiguous b128 (ak-style). Verified R25: attn
// conflicts 4.2M -> 0, 87.0 -> 81.0 us.
template <int OUTF32, int PERMB = 0>
__device__ __forceinline__ void gemm128_body(
    const bf16* __restrict__ A, const bf16* __restrict__ B, void* __restrict__ Cp,
    const float* __restrict__ bias, int m0, int n0, int N, int K) {
  __shared__ alignas(16) bf16 As[2][128 * 32];
  __shared__ alignas(16) bf16 Bs[2][128 * 32];
  const int tid = threadIdx.x;
  const int lane = tid & 63;
  const int w = tid >> 6;
  const int quad = lane >> 4;
  const int l16 = lane & 15;
  const int wr = (w >> 1) * 64;
  const int wc = (w & 1) * 64;

  const int srow = tid >> 2;
  const int skk = (tid & 3) * 8;
  const int srowB =
      PERMB ? ((srow & 0x23) | ((srow & 0x04) << 2) | ((srow & 0x18) >> 1)) : srow;
  const bf16* Ag = A + (long)(m0 + srow) * K + skk;
  const bf16* Bg = B + (long)(n0 + srowB) * K + skk;
  const long half = 64L * K;
  bf16* AsW0 = As[0] + w * 512;
  bf16* BsW0 = Bs[0] + w * 512;
  bf16* AsW1 = As[1] + w * 512;
  bf16* BsW1 = Bs[1] + w * 512;

  f32x4 acc[4][4];
#pragma unroll
  for (int i = 0; i < 4; ++i)
#pragma unroll
    for (int j = 0; j < 4; ++j) acc[i][j] = (f32x4){0.f, 0.f, 0.f, 0.f};

  for (int k0 = 0; k0 < K; k0 += 64) {
    async_copy16(Ag + k0, AsW0);
    async_copy16(Ag + half + k0, AsW0 + 2048);
    async_copy16(Bg + k0, BsW0);
    async_copy16(Bg + half + k0, BsW0 + 2048);
    async_copy16(Ag + k0 + 32, AsW1);
    async_copy16(Ag + half + k0 + 32, AsW1 + 2048);
    async_copy16(Bg + k0 + 32, BsW1);
    async_copy16(Bg + half + k0 + 32, BsW1 + 2048);
    __syncthreads();
#pragma unroll
    for (int p = 0; p < 2; ++p) {
      const bf16* AsP = As[p];
      const bf16* BsP = Bs[p];
      bf16x8 af[4], bfr[4];
#pragma unroll
      for (int i = 0; i < 4; ++i)
        af[i] = *(const bf16x8*)&AsP[(wr + i * 16 + l16) * 32 + quad * 8];
#pragma unroll
      for (int j = 0; j < 4; ++j)
        bfr[j] = *(const bf16x8*)&BsP[(wc + j * 16 + l16) * 32 + quad * 8];
#pragma unroll
      for (int i = 0; i < 4; ++i)
#pragma unroll
        for (int j = 0; j < 4; ++j) acc[i][j] = MFMA16(af[i], bfr[j], acc[i][j]);
    }
    __syncthreads();
  }

#pragma unroll
  for (int i = 0; i < 4; ++i)
#pragma unroll
    for (int j = 0; j < 4; ++j)
#pragma unroll
      for (int r = 0; r < 4; ++r) {
        long row = m0 + wr + i * 16 + quad * 4 + r;
        int col = n0 + wc + j * 16 + l16;
        if (OUTF32)
          ((float*)Cp)[row * N + col] = acc[i][j][r] + bias[col];
        else
          ((bf16*)Cp)[row * N + col] = (bf16)acc[i][j][r];
      }
}

// Combined QK-projection (bid<1024) + V^T (bid>=1024), SINGLE body call.
// launch_bounds(256,4): best measured. Index maps keep the LARGE operand (xb)
// XCD-local: same-tile readers 64 block-ids apart (64 % 8 == 0).
__global__ __launch_bounds__(256, 4) void k_gemm_qkv(
    const bf16* __restrict__ xb, const bf16* __restrict__ Wqk, bf16* __restrict__ QKb,
    const bf16* __restrict__ Wvb, bf16* __restrict__ VtG) {
  int bid = blockIdx.x;
  if (bid < 1024) {
    gemm128_body<0, 0>(xb, Wqk, QKb, nullptr,
                       (bid & 63) * 128, (bid >> 6) * 128, 2048, 1024);
  } else {
    int id = bid - 1024;
    // V^T with kv-permuted columns (PERMB=1) — consumed only by k_attn.
    gemm128_body<0, 1>(Wvb, xb, VtG, nullptr,
                       (id >> 6) * 128, (id & 63) * 128, 8192, 1024);
  }
}

__global__ __launch_bounds__(256, 4) void k_gemm_out(
    const bf16* __restrict__ Ab, const bf16* __restrict__ Wub, float* __restrict__ out,
    const float* __restrict__ bu) {
  gemm128_body<1, 0>(Ab, Wub, out, bu, blockIdx.x * 128, blockIdx.y * 128, 1024, 1024);
}

// --------------------------------------------------------- flash attention
// R28 post-mortem fix of R27's regression (81 -> 106 us): exp2f() lowered to
// the PRECISE OCML exp2 (range reduction, ~10 VALU ops/elem -> VALUBusy 64%),
// not a bare v_exp_f32. Fix: __builtin_amdgcn_exp2f — the compiler BUILTIN
// for v_exp_f32 (2^x). Builtin => instruction selection inserts the required
// trans-op hazard waits (unlike R5's raw inline asm, which raced).
// Everything else identical to R27: Wq pre-scaled at cvt (log2 domain, zero
// per-iter muls), raw bq loads, T5 setprio around MFMA clusters, R25's
// conflict-free LDS layout (pre-permuted VtG).
__global__ __launch_bounds__(256, 2) void k_attn(
    const bf16* __restrict__ Q, const bf16* __restrict__ Kb,
    const bf16* __restrict__ Vt, bf16* __restrict__ O) {
  __shared__ alignas(16) bf16 Ks[2][64 * 64];  // [buf][kv][d]   (swizzled 16B chunks)
  __shared__ alignas(16) bf16 Vs[2][64 * 64];  // [buf][d][klog] (swizzled 16B chunks)

  const int tid = threadIdx.x;
  const int lane = tid & 63;
  const int w = tid >> 6;
  const int quad = lane >> 4;
  const int l16 = lane & 15;
  const int hsw = l16 & 7;        // read-side swizzle key (row&7)
  const int bh = blockIdx.x;      // 0..63 (fast dim -> XCD = bh & 7)
  const int qt = blockIdx.y;      // 0..7 (256-row q tiles)
  const int bb = bh >> 4;
  const int h = bh & 15;
  const int hoff = h * 64;
  const long rowQ0 = (long)bb * 2048 + qt * 256;
  const long kv0 = (long)bb * 2048;

  // ---- Q B-frags direct from global (already scaled at cvt; raw loads)
  bf16x8 bq[4][2];
#pragma unroll
  for (int g = 0; g < 4; ++g)
#pragma unroll
    for (int ss = 0; ss < 2; ++ss)
      bq[g][ss] = *(const bf16x8*)(Q + (rowQ0 + w * 64 + g * 16 + l16) * 2048 +
                                   hoff + ss * 32 + quad * 8);

  f32x4 accO[4][4];
  f32x4 accS[4];
#pragma unroll
  for (int g = 0; g < 4; ++g) {
    accS[g] = (f32x4){0.f, 0.f, 0.f, 0.f};
#pragma unroll
    for (int t = 0; t < 4; ++t) accO[g][t] = (f32x4){0.f, 0.f, 0.f, 0.f};
  }

  // ---- staging addressing: thread L covers rows (L>>3) and (L>>3)+32 of the
  // 64-row tile; source col pre-swizzled so phys chunk p holds logical chunk
  // p^(row&7)  (same key as the reads). V columns are ALREADY kv-permuted in
  // VtG (GEMM-side), so V staging is identical in form to K staging.
  const int rr = tid >> 3;                       // 0..31
  const int cc8 = ((tid & 7) ^ (rr & 7)) * 8;    // source col (elems)
  const bf16* ksrc = Kb + (kv0 + rr) * 2048 + hoff + cc8;
  const bf16* vsrc = Vt + (long)(hoff + rr) * 8192 + kv0 + cc8;
  const int dstOff = w * 512;                    // wave-uniform LDS base (elems)

  // prologue: stage tile 0 into buf0
  async_copy16(ksrc, Ks[0] + dstOff);
  async_copy16(ksrc + 32 * 2048, Ks[0] + 2048 + dstOff);
  async_copy16(vsrc, Vs[0] + dstOff);
  async_copy16(vsrc + 32 * 8192, Vs[0] + 2048 + dstOff);
  ksrc += 64 * 2048;
  vsrc += 64;

  const bf16 onev = (bf16)1.0f;
  const bf16x8 ones8 = {onev, onev, onev, onev, onev, onev, onev, onev};

  for (int kt = 0; kt < 32; ++kt) {
    __syncthreads();  // drains this wave's stage(kt) (vmcnt 0) + syncs block
    if (kt < 31) {    // async prefetch of tile kt+1 into the other buffer
      bf16* kb = Ks[(kt + 1) & 1];
      bf16* vb = Vs[(kt + 1) & 1];
      async_copy16(ksrc, kb + dstOff);
      async_copy16(ksrc + 32 * 2048, kb + 2048 + dstOff);
      async_copy16(vsrc, vb + dstOff);
      async_copy16(vsrc + 32 * 8192, vb + 2048 + dstOff);
      ksrc += 64 * 2048;
      vsrc += 64;
    }
    const bf16* kbuf = Ks[kt & 1];
    const bf16* vbuf = Vs[kt & 1];

    // K A-frags: logical 16B chunk c = s*4+quad at row mt*16+l16, phys = c^hsw
    bf16x8 ak[4][2];
#pragma unroll
    for (int mt = 0; mt < 4; ++mt) {
      const int rb = (mt * 16 + l16) * 64;
      ak[mt][0] = *(const bf16x8*)&kbuf[rb + ((quad ^ hsw) * 8)];
      ak[mt][1] = *(const bf16x8*)&kbuf[rb + (((4 + quad) ^ hsw) * 8)];
    }
    // V B-frags: storage col pre-permuted, so logical chunk c = ss*4+quad at
    // row t*16+l16, phys = c^hsw — single b128, identical pattern to ak.
    bf16x8 bv[2][4];
#pragma unroll
    for (int ss = 0; ss < 2; ++ss)
#pragma unroll
      for (int t = 0; t < 4; ++t) {
        const int rb = (t * 16 + l16) * 64;
        bv[ss][t] = *(const bf16x8*)&vbuf[rb + (((ss * 4 + quad) ^ hsw) * 8)];
      }

#pragma unroll
    for (int g = 0; g < 4; ++g) {
      // S^T[kv][qrow] = K Q^T for this q-group (log2-domain: Wq pre-scaled)
      f32x4 st[4];
      __builtin_amdgcn_s_setprio(1);
#pragma unroll
      for (int mt = 0; mt < 4; ++mt) {
        st[mt] = (f32x4){0.f, 0.f, 0.f, 0.f};
        st[mt] = MFMA16(ak[mt][0], bq[g][0], st[mt]);
        st[mt] = MFMA16(ak[mt][1], bq[g][1], st[mt]);
      }
      __builtin_amdgcn_s_setprio(0);
      // max-free softmax in registers (permuted contraction axis):
      // apf[ss][4b+r] = exp2(st[2ss+b][r])  <->  kv = 32ss+16b+4quad+r
      // __builtin_amdgcn_exp2f = bare v_exp_f32 (compiler-inserted hazards)
      bf16x8 apf[2];
#pragma unroll
      for (int mt = 0; mt < 4; ++mt) {
#pragma unroll
        for (int r = 0; r < 4; ++r) {
          float pv = __builtin_amdgcn_exp2f(st[mt][r]);
          apf[mt >> 1][(mt & 1) * 4 + r] = (bf16)pv;
        }
      }
      // O += P V ; row sums via ones-column MFMA (no VALU adds, no shuffles)
      __builtin_amdgcn_s_setprio(1);
#pragma unroll
      for (int ss = 0; ss < 2; ++ss) {
#pragma unroll
        for (int t = 0; t < 4; ++t)
          accO[g][t] = MFMA16(apf[ss], bv[ss][t], accO[g][t]);
        accS[g] = MFMA16(apf[ss], ones8, accS[g]);
      }
      __builtin_amdgcn_s_setprio(0);
    }
  }

  // epilogue: accS[g][r] holds rowsum(qrow=quad*4+r) in every lane
#pragma unroll
  for (int g = 0; g < 4; ++g)
#pragma unroll
    for (int r = 0; r < 4; ++r) {
      float inv = 1.f / accS[g][r];
      long row = rowQ0 + w * 64 + g * 16 + quad * 4 + r;
#pragma unroll
      for (int t = 0; t < 4; ++t)
        O[row * 1024 + hoff + t * 16 + l16] = (bf16)(accO[g][t][r] * inv);
    }
}

// ----------------------------------------------------------------- launch
extern "C" void kernel_launch(void* const* d_in, const int* in_sizes, int n_in,
                              void* d_out, int out_size, void* d_ws, size_t ws_size,
                              hipStream_t stream) {
  const float* x  = (const float*)d_in[0];
  const float* Wk = (const float*)d_in[1];
  const float* Wq = (const float*)d_in[2];
  const float* Wv = (const float*)d_in[3];
  const float* Wu = (const float*)d_in[4];
  const float* bu = (const float*)d_in[5];
  float* out = (float*)d_out;

  const int XE = 4 * 2048 * 1024;  // 8388608
  const int WE = 1024 * 1024;      // 1048576

  bf16* p = (bf16*)d_ws;
  bf16* xb   = p; p += XE;
  bf16* Wqkb = p; p += 2 * WE;  // Wq rows (pre-scaled) | Wk rows
  bf16* Wvb  = p; p += WE;
  bf16* Wub  = p; p += WE;
  bf16* QKb  = p; p += 2 * XE;  // [8192][2048]: Q (log2-domain) | K
  bf16* VtG  = p; p += XE;      // V^T [1024][8192] (kv-permuted cols)
  bf16* Ab   = p; p += XE;      // attention output [8192][1024]

  CvtArgs ca;
  ca.src[0] = x;  ca.dst[0] = xb;
  ca.src[1] = Wq; ca.dst[1] = Wqkb;
  ca.src[2] = Wk; ca.dst[2] = Wqkb + WE;
  ca.src[3] = Wv; ca.dst[3] = Wvb;
  ca.src[4] = Wu; ca.dst[4] = Wub;
  ca.blk_start[0] = 0;
  ca.blk_start[1] = XE / 2048;                 // 4096
  ca.blk_start[2] = ca.blk_start[1] + WE / 2048;
  ca.blk_start[3] = ca.blk_start[2] + WE / 2048;
  ca.blk_start[4] = ca.blk_start[3] + WE / 2048;
  ca.blk_start[5] = ca.blk_start[4] + WE / 2048;  // 6144 total
  k_cvt_all<<<ca.blk_start[5], 256, 0, stream>>>(ca);

  k_gemm_qkv<<<1536, 256, 0, stream>>>(xb, Wqkb, QKb, Wvb, VtG);

  // grid: bh fast (XCD-aligned K/V reuse), qt slow
  k_attn<<<dim3(64, 8), 256, 0, stream>>>(QKb, QKb + 1024, VtG, Ab);

  k_gemm_out<<<dim3(64, 8), 256, 0, stream>>>(Ab, Wub, out, bu);
}